// Round 10
// baseline (462.385 us; speedup 1.0000x reference)
//
#include <hip/hip_runtime.h>

#define NN 8192
#define FIN 512
#define FOUT 64
#define LRELU_ALPHA 0.2f
#define LOG2E 1.4426950408889634f

typedef __attribute__((ext_vector_type(4))) float f32x4;
typedef __attribute__((ext_vector_type(4))) int i32x4;
typedef __attribute__((ext_vector_type(8))) __bf16 bf16x8;
typedef __attribute__((ext_vector_type(4))) __bf16 bf16x4;

#if __has_builtin(__builtin_amdgcn_exp2f)
#define EXP2F(x) __builtin_amdgcn_exp2f(x)
#else
#define EXP2F(x) exp2f(x)
#endif

// Kernel P: pack adj (int32 {0,1}, 268 MB) into a bitmask (8.4 MB) with
// PERFECTLY SEQUENTIAL reads (256B contiguous per instr — the fill-like
// pattern that hits ~6.6 TB/s). attn then reads bits from L2/L3 instead of
// streaming 268 MB of 64B scattered bursts (the measured residual cost:
// R3/R7/R8/R9 falsified occupancy/depth/burst/VALU theories).
// Bit layout: bit (col%64) of u64 word [row*128 + col/64] -> little-endian
// byte view: byte [row*1024 + col/8], bit col%8.
__global__ __launch_bounds__(256) void gat_pack(
    const int* __restrict__ adj, unsigned long long* __restrict__ packv)
{
    const int wid  = (blockIdx.x * 256 + threadIdx.x) >> 6;  // 0..32767
    const int lane = threadIdx.x & 63;
    const int row  = wid >> 2;
    const int qt   = wid & 3;                 // column quarter (2048 cols)

    const int* ap = adj + (size_t)row * NN + qt * 2048 + lane;

    unsigned long long mine = 0;
    #pragma unroll
    for (int k = 0; k < 32; ++k) {
        const int v = ap[k * 64];             // 256B contiguous per instr
        const unsigned long long b = __ballot(v > 0);  // cols [qt*2048+k*64, +64)
        if (lane == k) mine = b;
    }
    if (lane < 32)
        packv[(size_t)row * 128 + qt * 32 + lane] = mine;
}

// Kernel A: VERBATIM round-4/9 (~L2/VALU floor).
__global__ __launch_bounds__(256) void gat_wh(
    const float* __restrict__ x, const float* __restrict__ W,
    const float* __restrict__ A,
    __bf16* __restrict__ WhbT, float* __restrict__ s1, float* __restrict__ s2)
{
    const int wid  = (blockIdx.x * 256 + threadIdx.x) >> 6;
    const int lane = threadIdx.x & 63;
    const int cg   = lane & 15;
    const int kh   = lane >> 4;
    const int row0 = wid * 4;

    f32x4 acc[4];
    #pragma unroll
    for (int r_ = 0; r_ < 4; ++r_) acc[r_] = (f32x4){0.f, 0.f, 0.f, 0.f};

    const float* xb   = x + (size_t)row0 * FIN + kh * 128;
    const float* wcol = W + cg * 4 + (size_t)kh * 128 * FOUT;

    #pragma unroll 2
    for (int k = 0; k < 128; k += 4) {
        f32x4 wv[4];
        #pragma unroll
        for (int u = 0; u < 4; ++u)
            wv[u] = *reinterpret_cast<const f32x4*>(wcol + (size_t)(k + u) * FOUT);
        #pragma unroll
        for (int r_ = 0; r_ < 4; ++r_) {
            f32x4 xv = *reinterpret_cast<const f32x4*>(xb + (size_t)r_ * FIN + k);
            acc[r_] += xv[0] * wv[0];
            acc[r_] += xv[1] * wv[1];
            acc[r_] += xv[2] * wv[2];
            acc[r_] += xv[3] * wv[3];
        }
    }

    #pragma unroll
    for (int r_ = 0; r_ < 4; ++r_) {
        #pragma unroll
        for (int u = 0; u < 4; ++u) {
            acc[r_][u] += __shfl_xor(acc[r_][u], 16);
            acc[r_][u] += __shfl_xor(acc[r_][u], 32);
        }
    }

    f32x4 a1v = *reinterpret_cast<const f32x4*>(A + cg * 4);
    f32x4 a2v = *reinterpret_cast<const f32x4*>(A + FOUT + cg * 4);
    #pragma unroll
    for (int r_ = 0; r_ < 4; ++r_) {
        float s1p = acc[r_][0]*a1v[0] + acc[r_][1]*a1v[1] + acc[r_][2]*a1v[2] + acc[r_][3]*a1v[3];
        float s2p = acc[r_][0]*a2v[0] + acc[r_][1]*a2v[1] + acc[r_][2]*a2v[2] + acc[r_][3]*a2v[3];
        #pragma unroll
        for (int off = 1; off < 16; off <<= 1) {
            s1p += __shfl_xor(s1p, off);
            s2p += __shfl_xor(s2p, off);
        }
        if (lane == 0) { s1[row0 + r_] = s1p; s2[row0 + r_] = s2p; }
    }

    if (kh == 0) {
        #pragma unroll
        for (int u = 0; u < 4; ++u) {
            bf16x4 pk;
            pk[0] = (__bf16)acc[0][u];
            pk[1] = (__bf16)acc[1][u];
            pk[2] = (__bf16)acc[2][u];
            pk[3] = (__bf16)acc[3][u];
            *reinterpret_cast<bf16x4*>(WhbT + (size_t)(cg * 4 + u) * NN + row0) = pk;
        }
    }
}

// Kernel B: round-9 structure & arithmetic VERBATIM; the two scattered
// i32x4 adj loads per half are replaced by ONE ubyte bitmask load (L2-hot,
// 8 MB table). Mask test: bit i of the byte <-> adj(row, jc+q*8+i) > 0.
__global__ __launch_bounds__(256) void gat_attn(
    const unsigned char* __restrict__ pack8, const __bf16* __restrict__ WhbT,
    const float* __restrict__ s1g, const float* __restrict__ s2g,
    const float* __restrict__ bias, float* __restrict__ out)
{
    __shared__ float s2l[NN];             // s2 * log2(e)
    __shared__ float red[4];
    __shared__ float ol[4][16];
    __shared__ float oacc[4][16][FOUT];

    const int tid  = threadIdx.x;
    const int w    = tid >> 6;
    const int lane = tid & 63;
    const int r    = lane & 15;           // MFMA A-row / C-col
    const int q    = lane >> 4;           // k-chunk q*8..q*8+7
    const int row0 = blockIdx.x * 16;

    float mx = -3.0e38f;
    for (int i = tid; i < NN / 4; i += 256) {
        f32x4 v = reinterpret_cast<const f32x4*>(s2g)[i];
        v *= LOG2E;
        reinterpret_cast<f32x4*>(s2l)[i] = v;
        mx = fmaxf(mx, fmaxf(fmaxf(v[0], v[1]), fmaxf(v[2], v[3])));
    }
    #pragma unroll
    for (int off = 1; off < 64; off <<= 1)
        mx = fmaxf(mx, __shfl_xor(mx, off));
    if (lane == 0) red[w] = mx;
    __syncthreads();
    const float s2maxl = fmaxf(fmaxf(red[0], red[1]), fmaxf(red[2], red[3]));

    const float s1l = s1g[row0 + r] * LOG2E;
    const float tM  = s1l + s2maxl;
    const float Ml  = fmaxf(tM, LRELU_ALPHA * tM);   // lrelu in log2 domain
    const float c1  = s1l - Ml;
    const float c2  = LRELU_ALPHA * s1l - Ml;

    const __bf16 oneb = (__bf16)1.0f;
    const bf16x8 onesv = {oneb, oneb, oneb, oneb, oneb, oneb, oneb, oneb};

    f32x4 acc0 = {0,0,0,0}, acc1 = {0,0,0,0}, acc2 = {0,0,0,0}, acc3 = {0,0,0,0};
    f32x4 accL = {0,0,0,0};

    // per-lane bitmask base: byte (row0+r)*1024 + w*256 + q  (+ it*8 + c*4)
    const unsigned char* mkp = pack8 + (size_t)(row0 + r) * (NN / 8) + (w << 8) + q;

    const __bf16* wpb  = WhbT + (w << 11) + (q << 3);
    const __bf16* wp0  = wpb + (size_t)(0 * 16 + r) * NN;
    const __bf16* wp1  = wpb + (size_t)(1 * 16 + r) * NN;
    const __bf16* wp2  = wpb + (size_t)(2 * 16 + r) * NN;
    const __bf16* wp3  = wpb + (size_t)(3 * 16 + r) * NN;
    const float*  s2p_ = s2l + (w << 11) + (q << 3);

    for (int it = 0; it < 32; ++it) {                 // 64 cols per iteration
        const int j0 = it << 6;
        #pragma unroll
        for (int c = 0; c < 2; ++c) {
            const int jc = j0 + (c << 5);
            const unsigned int mb = mkp[(it << 3) + (c << 2)];
            bf16x8 b0 = *reinterpret_cast<const bf16x8*>(wp0 + jc);
            bf16x8 b1 = *reinterpret_cast<const bf16x8*>(wp1 + jc);
            bf16x8 b2 = *reinterpret_cast<const bf16x8*>(wp2 + jc);
            bf16x8 b3 = *reinterpret_cast<const bf16x8*>(wp3 + jc);
            f32x4 s2a = *reinterpret_cast<const f32x4*>(s2p_ + jc);
            f32x4 s2c = *reinterpret_cast<const f32x4*>(s2p_ + jc + 4);

            bf16x8 af;
            #pragma unroll
            for (int i = 0; i < 4; ++i) {
                float g0 = fmaxf(c1 + s2a[i], fmaf(LRELU_ALPHA, s2a[i], c2));
                g0 = (mb & (1u << i)) ? g0 : -3.0e38f;       // masked -> exp2 -> 0
                af[i] = (__bf16)EXP2F(g0);
                float g1 = fmaxf(c1 + s2c[i], fmaf(LRELU_ALPHA, s2c[i], c2));
                g1 = (mb & (16u << i)) ? g1 : -3.0e38f;      // bit i+4
                af[i + 4] = (__bf16)EXP2F(g1);
            }
            acc0 = __builtin_amdgcn_mfma_f32_16x16x32_bf16(af, b0, acc0, 0, 0, 0);
            acc1 = __builtin_amdgcn_mfma_f32_16x16x32_bf16(af, b1, acc1, 0, 0, 0);
            acc2 = __builtin_amdgcn_mfma_f32_16x16x32_bf16(af, b2, acc2, 0, 0, 0);
            acc3 = __builtin_amdgcn_mfma_f32_16x16x32_bf16(af, b3, acc3, 0, 0, 0);
            accL = __builtin_amdgcn_mfma_f32_16x16x32_bf16(af, onesv, accL, 0, 0, 0);
        }
    }

    // l lives in accL: C row = q*4+reg, identical across cols (B uniform)
    if (r == 0) {
        #pragma unroll
        for (int reg = 0; reg < 4; ++reg) ol[w][(q << 2) + reg] = accL[reg];
    }
    #pragma unroll
    for (int reg = 0; reg < 4; ++reg) {
        oacc[w][(q << 2) + reg][0 * 16 + r] = acc0[reg];
        oacc[w][(q << 2) + reg][1 * 16 + r] = acc1[reg];
        oacc[w][(q << 2) + reg][2 * 16 + r] = acc2[reg];
        oacc[w][(q << 2) + reg][3 * 16 + r] = acc3[reg];
    }
    __syncthreads();

    for (int o = tid; o < 16 * FOUT; o += 256) {
        const int rr = o >> 6;
        const int f  = o & 63;
        const float L = ol[0][rr] + ol[1][rr] + ol[2][rr] + ol[3][rr];
        const float O = oacc[0][rr][f] + oacc[1][rr][f] + oacc[2][rr][f] + oacc[3][rr][f];
        out[(size_t)(row0 + rr) * FOUT + f] = O / L + bias[f];
    }
}

extern "C" void kernel_launch(void* const* d_in, const int* in_sizes, int n_in,
                              void* d_out, int out_size, void* d_ws, size_t ws_size,
                              hipStream_t stream)
{
    const float* x    = (const float*)d_in[0];
    const int*   adj  = (const int*)d_in[1];
    const float* W    = (const float*)d_in[2];
    const float* bias = (const float*)d_in[3];
    const float* A    = (const float*)d_in[4];
    float* out = (float*)d_out;

    // workspace: WhbT (1 MB) | s1 (32 KB) | s2 (32 KB) | packv (8 MB)
    char* ws = (char*)d_ws;
    __bf16* WhbT = (__bf16*)ws;
    float*  s1   = (float*)(ws + (size_t)FOUT * NN * sizeof(__bf16));
    float*  s2   = s1 + NN;
    unsigned long long* packv = (unsigned long long*)(s2 + NN);

    gat_pack<<<dim3(NN * 4 / 4), dim3(256), 0, stream>>>(adj, packv);   // 8192 blocks
    gat_wh<<<dim3(512), dim3(256), 0, stream>>>(x, W, A, WhbT, s1, s2);
    gat_attn<<<dim3(NN / 16), dim3(256), 0, stream>>>((const unsigned char*)packv,
                                                      WhbT, s1, s2, bias, out);
}

// Round 11
// 405.396 us; speedup vs baseline: 1.1406x; 1.1406x over previous
//
#include <hip/hip_runtime.h>

#define NN 8192
#define FIN 512
#define FOUT 64
#define LRELU_ALPHA 0.2f
#define LOG2E 1.4426950408889634f

typedef __attribute__((ext_vector_type(4))) float f32x4;
typedef __attribute__((ext_vector_type(4))) int i32x4;
typedef __attribute__((ext_vector_type(8))) __bf16 bf16x8;

#if __has_builtin(__builtin_amdgcn_exp2f)
#define EXP2F(x) __builtin_amdgcn_exp2f(x)
#else
#define EXP2F(x) exp2f(x)
#endif

// Kernel A: round-4/9 compute VERBATIM; the ONLY change is the output layout:
// Wh is stored pre-permuted into exact MFMA B-fragment order ("Wpk") so that
// attn's 4 B-operand loads per half are 1KB FULLY CONTIGUOUS per wave
// (vs 16 rows x 16KB stride = ~32 cacheline touches per instr — the
// occupancy/schedule/traffic-invariant TA cost R3/R7/R8/R10 could not kill).
// Layout: Wpk[((c*4+fb)*64 + q*16 + rr)*8 + j] = Wh[c*32+q*8+j][fb*16+rr].
__global__ __launch_bounds__(256) void gat_wh(
    const float* __restrict__ x, const float* __restrict__ W,
    const float* __restrict__ A,
    __bf16* __restrict__ Wpk, float* __restrict__ s1, float* __restrict__ s2)
{
    const int wid  = (blockIdx.x * 256 + threadIdx.x) >> 6;
    const int lane = threadIdx.x & 63;
    const int cg   = lane & 15;
    const int kh   = lane >> 4;
    const int row0 = wid * 4;

    f32x4 acc[4];
    #pragma unroll
    for (int r_ = 0; r_ < 4; ++r_) acc[r_] = (f32x4){0.f, 0.f, 0.f, 0.f};

    const float* xb   = x + (size_t)row0 * FIN + kh * 128;
    const float* wcol = W + cg * 4 + (size_t)kh * 128 * FOUT;

    #pragma unroll 2
    for (int k = 0; k < 128; k += 4) {
        f32x4 wv[4];
        #pragma unroll
        for (int u = 0; u < 4; ++u)
            wv[u] = *reinterpret_cast<const f32x4*>(wcol + (size_t)(k + u) * FOUT);
        #pragma unroll
        for (int r_ = 0; r_ < 4; ++r_) {
            f32x4 xv = *reinterpret_cast<const f32x4*>(xb + (size_t)r_ * FIN + k);
            acc[r_] += xv[0] * wv[0];
            acc[r_] += xv[1] * wv[1];
            acc[r_] += xv[2] * wv[2];
            acc[r_] += xv[3] * wv[3];
        }
    }

    // butterfly over lane bits 4,5: ALL lanes now hold the full-K dot products
    #pragma unroll
    for (int r_ = 0; r_ < 4; ++r_) {
        #pragma unroll
        for (int u = 0; u < 4; ++u) {
            acc[r_][u] += __shfl_xor(acc[r_][u], 16);
            acc[r_][u] += __shfl_xor(acc[r_][u], 32);
        }
    }

    f32x4 a1v = *reinterpret_cast<const f32x4*>(A + cg * 4);
    f32x4 a2v = *reinterpret_cast<const f32x4*>(A + FOUT + cg * 4);
    #pragma unroll
    for (int r_ = 0; r_ < 4; ++r_) {
        float s1p = acc[r_][0]*a1v[0] + acc[r_][1]*a1v[1] + acc[r_][2]*a1v[2] + acc[r_][3]*a1v[3];
        float s2p = acc[r_][0]*a2v[0] + acc[r_][1]*a2v[1] + acc[r_][2]*a2v[2] + acc[r_][3]*a2v[3];
        #pragma unroll
        for (int off = 1; off < 16; off <<= 1) {
            s1p += __shfl_xor(s1p, off);
            s2p += __shfl_xor(s2p, off);
        }
        if (lane == 0) { s1[row0 + r_] = s1p; s2[row0 + r_] = s2p; }
    }

    // permuted store: lane (cg,kh) stores feat = cg*4 + kh for its 4 nodes.
    // feat -> fb = cg>>2, rr = (cg&3)*4 + kh; node -> c=node>>5, q=(node>>3)&3, j=node&7.
    {
        const int fb = cg >> 2;
        const int rr = ((cg & 3) << 2) + kh;
        #pragma unroll
        for (int r_ = 0; r_ < 4; ++r_) {
            const int node = row0 + r_;
            const int c    = node >> 5;
            const int qq   = (node >> 3) & 3;
            const int j    = node & 7;
            Wpk[((size_t)((c << 2) + fb) << 9) + (qq << 7) + (rr << 3) + j]
                = (__bf16)acc[r_][kh];
        }
    }
}

// Kernel B: round-9 VERBATIM (direct adj loads, fixed-M + c1/c2 fold, in-loop
// exp2, accL ones-MFMA row-sum) — except the 4 B-operand loads now read the
// fragment-linear Wpk: one base + immediate offsets 0/1/2/3 KB, each load
// 1KB contiguous across the wave. Fragment CONTENTS are bit-identical to R9.
__global__ __launch_bounds__(256) void gat_attn(
    const int* __restrict__ adj, const __bf16* __restrict__ Wpk,
    const float* __restrict__ s1g, const float* __restrict__ s2g,
    const float* __restrict__ bias, float* __restrict__ out)
{
    __shared__ float s2l[NN];             // s2 * log2(e)
    __shared__ float red[4];
    __shared__ float ol[4][16];
    __shared__ float oacc[4][16][FOUT];

    const int tid  = threadIdx.x;
    const int w    = tid >> 6;
    const int lane = tid & 63;
    const int r    = lane & 15;           // MFMA A-row / C-col
    const int q    = lane >> 4;           // k-chunk q*8..q*8+7
    const int row0 = blockIdx.x * 16;

    float mx = -3.0e38f;
    for (int i = tid; i < NN / 4; i += 256) {
        f32x4 v = reinterpret_cast<const f32x4*>(s2g)[i];
        v *= LOG2E;
        reinterpret_cast<f32x4*>(s2l)[i] = v;
        mx = fmaxf(mx, fmaxf(fmaxf(v[0], v[1]), fmaxf(v[2], v[3])));
    }
    #pragma unroll
    for (int off = 1; off < 64; off <<= 1)
        mx = fmaxf(mx, __shfl_xor(mx, off));
    if (lane == 0) red[w] = mx;
    __syncthreads();
    const float s2maxl = fmaxf(fmaxf(red[0], red[1]), fmaxf(red[2], red[3]));

    const float s1l = s1g[row0 + r] * LOG2E;
    const float tM  = s1l + s2maxl;
    const float Ml  = fmaxf(tM, LRELU_ALPHA * tM);   // lrelu in log2 domain
    const float c1  = s1l - Ml;
    const float c2  = LRELU_ALPHA * s1l - Ml;

    const __bf16 oneb = (__bf16)1.0f;
    const bf16x8 onesv = {oneb, oneb, oneb, oneb, oneb, oneb, oneb, oneb};

    f32x4 acc0 = {0,0,0,0}, acc1 = {0,0,0,0}, acc2 = {0,0,0,0}, acc3 = {0,0,0,0};
    f32x4 accL = {0,0,0,0};

    const int*    adjp = adj + (size_t)(row0 + r) * NN + (w << 11) + (q << 3);
    // fragment-linear Wh: per-wave strip = 256KB (1<<17 elements), per-lane 16B
    const __bf16* wq   = Wpk + ((size_t)w << 17) + ((size_t)lane << 3);
    const float*  s2p_ = s2l + (w << 11) + (q << 3);

    for (int it = 0; it < 32; ++it) {                 // 64 cols per iteration
        const int j0 = it << 6;
        #pragma unroll
        for (int c = 0; c < 2; ++c) {
            const int jc = j0 + (c << 5);
            const __bf16* ph = wq + ((size_t)(jc >> 5) << 11);   // chunk*2048 elems
            i32x4 av0 = *reinterpret_cast<const i32x4*>(adjp + jc);
            i32x4 av1 = *reinterpret_cast<const i32x4*>(adjp + jc + 4);
            bf16x8 b0 = *reinterpret_cast<const bf16x8*>(ph);
            bf16x8 b1 = *reinterpret_cast<const bf16x8*>(ph + 512);
            bf16x8 b2 = *reinterpret_cast<const bf16x8*>(ph + 1024);
            bf16x8 b3 = *reinterpret_cast<const bf16x8*>(ph + 1536);
            f32x4 s2a = *reinterpret_cast<const f32x4*>(s2p_ + jc);
            f32x4 s2c = *reinterpret_cast<const f32x4*>(s2p_ + jc + 4);

            bf16x8 af;
            #pragma unroll
            for (int i = 0; i < 4; ++i) {
                float g0 = fmaxf(c1 + s2a[i], fmaf(LRELU_ALPHA, s2a[i], c2));
                g0 = (av0[i] > 0) ? g0 : -3.0e38f;     // masked -> exp2 -> 0
                af[i] = (__bf16)EXP2F(g0);
                float g1 = fmaxf(c1 + s2c[i], fmaf(LRELU_ALPHA, s2c[i], c2));
                g1 = (av1[i] > 0) ? g1 : -3.0e38f;
                af[i + 4] = (__bf16)EXP2F(g1);
            }
            acc0 = __builtin_amdgcn_mfma_f32_16x16x32_bf16(af, b0, acc0, 0, 0, 0);
            acc1 = __builtin_amdgcn_mfma_f32_16x16x32_bf16(af, b1, acc1, 0, 0, 0);
            acc2 = __builtin_amdgcn_mfma_f32_16x16x32_bf16(af, b2, acc2, 0, 0, 0);
            acc3 = __builtin_amdgcn_mfma_f32_16x16x32_bf16(af, b3, acc3, 0, 0, 0);
            accL = __builtin_amdgcn_mfma_f32_16x16x32_bf16(af, onesv, accL, 0, 0, 0);
        }
    }

    // l lives in accL: C row = q*4+reg, identical across cols (B uniform)
    if (r == 0) {
        #pragma unroll
        for (int reg = 0; reg < 4; ++reg) ol[w][(q << 2) + reg] = accL[reg];
    }
    #pragma unroll
    for (int reg = 0; reg < 4; ++reg) {
        oacc[w][(q << 2) + reg][0 * 16 + r] = acc0[reg];
        oacc[w][(q << 2) + reg][1 * 16 + r] = acc1[reg];
        oacc[w][(q << 2) + reg][2 * 16 + r] = acc2[reg];
        oacc[w][(q << 2) + reg][3 * 16 + r] = acc3[reg];
    }
    __syncthreads();

    for (int o = tid; o < 16 * FOUT; o += 256) {
        const int rr = o >> 6;
        const int f  = o & 63;
        const float L = ol[0][rr] + ol[1][rr] + ol[2][rr] + ol[3][rr];
        const float O = oacc[0][rr][f] + oacc[1][rr][f] + oacc[2][rr][f] + oacc[3][rr][f];
        out[(size_t)(row0 + rr) * FOUT + f] = O / L + bias[f];
    }
}

extern "C" void kernel_launch(void* const* d_in, const int* in_sizes, int n_in,
                              void* d_out, int out_size, void* d_ws, size_t ws_size,
                              hipStream_t stream)
{
    const float* x    = (const float*)d_in[0];
    const int*   adj  = (const int*)d_in[1];
    const float* W    = (const float*)d_in[2];
    const float* bias = (const float*)d_in[3];
    const float* A    = (const float*)d_in[4];
    float* out = (float*)d_out;

    // workspace: Wpk (1 MB) | s1 (32 KB) | s2 (32 KB)
    char* ws = (char*)d_ws;
    __bf16* Wpk = (__bf16*)ws;
    float*  s1  = (float*)(ws + (size_t)FOUT * NN * sizeof(__bf16));
    float*  s2  = s1 + NN;

    gat_wh<<<dim3(512), dim3(256), 0, stream>>>(x, W, A, Wpk, s1, s2);
    gat_attn<<<dim3(NN / 16), dim3(256), 0, stream>>>(adj, Wpk, s1, s2, bias, out);
}